// Round 6
// baseline (76.427 us; speedup 1.0000x reference)
//
#include <hip/hip_runtime.h>
#include <hip/hip_bf16.h>

#define NN 32768
#define LN_EPS 1e-5f

typedef float v4f __attribute__((ext_vector_type(4)));
typedef __attribute__((ext_vector_type(8))) short bf16x8;   // 8 bf16 in 4 VGPRs
typedef __attribute__((ext_vector_type(4))) float f32x4;

// TRUNCATION split: f = hi + lo, bf16 hi = trunc(f), bf16 lo = trunc(f - hi).
__device__ __forceinline__ void bsplit(float f, short &hi, short &lo) {
  unsigned u; __builtin_memcpy(&u, &f, 4);
  unsigned hb = u & 0xffff0000u;
  hi = (short)(u >> 16);
  float hf; __builtin_memcpy(&hf, &hb, 4);
  float lf = f - hf;
  unsigned ul; __builtin_memcpy(&ul, &lf, 4);
  lo = (short)(ul >> 16);
}

// truncation f32 -> bf16 bits.
__device__ __forceinline__ unsigned short bf16u(float f) {
  unsigned u; __builtin_memcpy(&u, &f, 4);
  return (unsigned short)(u >> 16);
}

// K1: kproj partials via MFMA (affine-LN factorization, split-bf16 x3).
// grid 512 (= b(4) x chunk(128) of 256 n), block 256 = 4 waves.
__global__ __launch_bounds__(256) void k1_mfma(
    const float* __restrict__ skip, const float* __restrict__ EF2,
    float* __restrict__ partials)
{
  __shared__ float cred[4752];      // [row<144][33-pad]

  int bx = blockIdx.x, t = threadIdx.x;
  int b = bx >> 7, chunk = bx & 127;
  int w = t >> 6, l = t & 63;
  int i16 = l & 15, kc = (l >> 4) << 3;

  f32x4 acc[9][2];
#pragma unroll
  for (int mt = 0; mt < 9; ++mt)
#pragma unroll
    for (int nt = 0; nt < 2; ++nt)
      acc[mt][nt] = (f32x4){0.f, 0.f, 0.f, 0.f};

#pragma unroll
  for (int it = 0; it < 2; ++it) {
    int n0 = chunk * 256 + w * 64 + it * 32;
    int kt = chunk * 8 + w * 2 + it;

    bf16x8 Bh[2], Bl[2];
    const float* eb = EF2 + (size_t)(kt * 32 + kc) * 32;
#pragma unroll
    for (int nt = 0; nt < 2; ++nt) {
#pragma unroll
      for (int j = 0; j < 8; ++j) {
        float e = eb[(size_t)j * 32 + nt * 16 + i16];
        short hh, ll; bsplit(e, hh, ll);
        Bh[nt][j] = hh; Bl[nt][j] = ll;
      }
    }

    const float* ap = skip + (size_t)(b * 128) * NN + n0 + kc;
    float af[8][8];
#pragma unroll
    for (int mt = 0; mt < 8; ++mt) {
      const float* rp = ap + (size_t)(mt * 16 + i16) * NN;
      float4 a0 = *(const float4*)(rp);
      float4 a1 = *(const float4*)(rp + 4);
      af[mt][0] = a0.x; af[mt][1] = a0.y; af[mt][2] = a0.z; af[mt][3] = a0.w;
      af[mt][4] = a1.x; af[mt][5] = a1.y; af[mt][6] = a1.z; af[mt][7] = a1.w;
    }

    float cs[8], sq[8];
#pragma unroll
    for (int j = 0; j < 8; ++j) {
      float s = 0.f, q = 0.f;
#pragma unroll
      for (int mt = 0; mt < 8; ++mt) { s += af[mt][j]; q = fmaf(af[mt][j], af[mt][j], q); }
      cs[j] = s; sq[j] = q;
    }
#pragma unroll
    for (int m = 1; m <= 8; m <<= 1) {
#pragma unroll
      for (int j = 0; j < 8; ++j) {
        cs[j] += __shfl_xor(cs[j], m);
        sq[j] += __shfl_xor(sq[j], m);
      }
    }
    float rs[8], mr[8];
#pragma unroll
    for (int j = 0; j < 8; ++j) {
      float mu = cs[j] * (1.f / 128.f);
      rs[j] = rsqrtf(sq[j] * (1.f / 128.f) - mu * mu + LN_EPS);
      mr[j] = mu * rs[j];
    }

#pragma unroll
    for (int mt = 0; mt < 8; ++mt) {
      bf16x8 Ah, Al;
#pragma unroll
      for (int j = 0; j < 8; ++j) {
        short h, lo; bsplit(af[mt][j] * rs[j], h, lo);
        Ah[j] = h; Al[j] = lo;
      }
#pragma unroll
      for (int nt = 0; nt < 2; ++nt) {
        acc[mt][nt] = __builtin_amdgcn_mfma_f32_16x16x32_bf16(Ah, Bh[nt], acc[mt][nt], 0, 0, 0);
        acc[mt][nt] = __builtin_amdgcn_mfma_f32_16x16x32_bf16(Al, Bh[nt], acc[mt][nt], 0, 0, 0);
        acc[mt][nt] = __builtin_amdgcn_mfma_f32_16x16x32_bf16(Ah, Bl[nt], acc[mt][nt], 0, 0, 0);
      }
    }
    {
      bf16x8 Ah, Al;
#pragma unroll
      for (int j = 0; j < 8; ++j) {
        float v = (i16 == 0) ? mr[j] : ((i16 == 1) ? 1.f : 0.f);
        short h, lo; bsplit(v, h, lo);
        Ah[j] = h; Al[j] = lo;
      }
#pragma unroll
      for (int nt = 0; nt < 2; ++nt) {
        acc[8][nt] = __builtin_amdgcn_mfma_f32_16x16x32_bf16(Ah, Bh[nt], acc[8][nt], 0, 0, 0);
        acc[8][nt] = __builtin_amdgcn_mfma_f32_16x16x32_bf16(Al, Bh[nt], acc[8][nt], 0, 0, 0);
        acc[8][nt] = __builtin_amdgcn_mfma_f32_16x16x32_bf16(Ah, Bl[nt], acc[8][nt], 0, 0, 0);
      }
    }
  }

  int rbase = (l >> 4) * 4;
  for (int ww = 0; ww < 4; ++ww) {
    __syncthreads();
    if (w == ww) {
#pragma unroll
      for (int mt = 0; mt < 9; ++mt)
#pragma unroll
        for (int nt = 0; nt < 2; ++nt)
#pragma unroll
          for (int r = 0; r < 4; ++r) {
            int addr = (mt * 16 + rbase + r) * 33 + nt * 16 + i16;
            if (ww == 0) cred[addr] = acc[mt][nt][r];
            else         cred[addr] += acc[mt][nt][r];
          }
    }
  }
  __syncthreads();
  float* pw = partials + (size_t)bx * 4608;
#pragma unroll
  for (int i = 0; i < 18; ++i) {
    int idx = t + i * 256;
    pw[idx] = cred[(idx >> 5) * 33 + (idx & 31)];
  }
}

// K2red: reduce 128 chunk-partials per (b,row) for rows 0..129.
// grid dim3(130, 4), block 256.
__global__ __launch_bounds__(256) void k2_red(
    const float* __restrict__ partials, float* __restrict__ raw)
{
  __shared__ float red[8][32];
  int row = blockIdx.x;      // 0..129
  int b   = blockIdx.y;      // 0..3
  int t = threadIdx.x;
  int p = t & 31, grp = t >> 5;
  const float* pp = partials + ((size_t)(b * 128 + grp * 16)) * 4608 + row * 32 + p;
  float s = 0.f;
  for (int i = 0; i < 16; ++i)
    s += pp[(size_t)i * 4608];
  red[grp][p] = s;
  __syncthreads();
  if (t < 32) {
    float tot = 0.f;
#pragma unroll
    for (int g2 = 0; g2 < 8; ++g2) tot += red[g2][t];
    raw[((size_t)b * 130 + row) * 32 + t] = tot;
  }
}

// K2post: per (b,h): affine -> kpw, W1/B1, vproj; pack kfrag/vfrag.
// grid 16, block 64.
__global__ __launch_bounds__(64) void k2_post(
    const float* __restrict__ raw, const float* __restrict__ gf,
    const float* __restrict__ EF1, const float* __restrict__ lnw,
    const float* __restrict__ lnb,
    float* __restrict__ W1, float* __restrict__ B1,
    short* __restrict__ kfrag, short* __restrict__ vfrag)
{
  __shared__ float kpw_s[32][33];   // [d][p]
  __shared__ float vps_s[32][33];   // [p'][k]
  int bh = blockIdx.x, l = threadIdx.x;
  int b = bh >> 2, h = bh & 3;
  int p = l & 31, half = l >> 5;
  const float* rb = raw + (size_t)b * 130 * 32;
  float T = rb[128 * 32 + p];
  float U = rb[129 * 32 + p];
  float w1a = 0.f, b1a = 0.f;
#pragma unroll
  for (int d2 = 0; d2 < 16; ++d2) {
    int d = half * 16 + d2, c = h * 32 + d;
    float tot = rb[c * 32 + p];
    float kp = lnw[c] * (tot - T) + lnb[c] * U;
    float kw = lnw[c] * kp;
    kpw_s[d][p] = kw;
    w1a += kw;
    b1a += lnb[c] * kp;
  }
  w1a += __shfl_xor(w1a, 32);
  b1a += __shfl_xor(b1a, 32);
  if (half == 0) {
    W1[bh * 32 + p] = w1a;
    B1[bh * 32 + p] = b1a;
  }
  {
    float acc[16];
#pragma unroll
    for (int kk = 0; kk < 16; ++kk) acc[kk] = 0.f;
    for (int g = 0; g < 64; ++g) {
      float gv = gf[((size_t)(b * 64 + g)) * 128 + h * 32 + p];
      const float* e1 = EF1 + g * 32 + half * 16;
#pragma unroll
      for (int kk = 0; kk < 16; ++kk) acc[kk] += gv * e1[kk];
    }
#pragma unroll
    for (int kk = 0; kk < 16; ++kk) vps_s[p][half * 16 + kk] = acc[kk];
  }
  __syncthreads();
  int i16 = l & 15, g4 = l >> 4;
#pragma unroll
  for (int pt = 0; pt < 2; ++pt) {
    bf16x8 hi8, lo8;
#pragma unroll
    for (int j = 0; j < 8; ++j) {
      short hh, ll; bsplit(kpw_s[g4 * 8 + j][pt * 16 + i16], hh, ll);
      hi8[j] = hh; lo8[j] = ll;
    }
    *(bf16x8*)(kfrag + (size_t)bh * 2048 + pt * 1024 + l * 8) = hi8;
    *(bf16x8*)(kfrag + (size_t)bh * 2048 + pt * 1024 + 512 + l * 8) = lo8;
  }
#pragma unroll
  for (int kt = 0; kt < 2; ++kt) {
    bf16x8 hi8, lo8;
#pragma unroll
    for (int j = 0; j < 8; ++j) {
      short hh, ll; bsplit(vps_s[g4 * 8 + j][kt * 16 + i16], hh, ll);
      hi8[j] = hh; lo8[j] = ll;
    }
    *(bf16x8*)(vfrag + (size_t)bh * 2048 + kt * 1024 + l * 8) = hi8;
    *(bf16x8*)(vfrag + (size_t)bh * 2048 + kt * 1024 + 512 + l * 8) = lo8;
  }
}

// K3: fused out-LN-stats + attention via MFMA.
// READ-GRANULE fix (this round's single change): block = 128 n x 128 c,
// grid 1024 (= b(4) x chunk(256)), block 512 = 8 waves.
//  - staging reads 512 B CONTIGUOUS per c-row (k1's proven-fast granule)
//    instead of 128 B: half-wave (32 lanes) x float4 per row, 16 rows/pass,
//    8 passes. LN partials fused into staging regs.
//  - q slab [128 c][129 n-pad] (66 KB); pstat[2][128][9] holds per-wave LN
//    partials, finalized into registers (mrr) after barrier 1, then the
//    SAME scratch region is reused as the per-wave P-transpose buffer
//    behind barrier 2 (no overlap hazard: all pstat reads precede it).
//  - per wave: head h = w&3, two 32-n sub-chunks {w>>2, (w>>2)+2}; the
//    per-sub-chunk QK/softmax/P-transpose/PV/packed-store is byte-identical
//    to the round-2 passing version. xws layout and k4 unchanged.
__global__ __launch_bounds__(512) void k3_attn(
    const float* __restrict__ outp, const short* __restrict__ kfrag,
    const short* __restrict__ vfrag, const float* __restrict__ W1,
    const float* __restrict__ B1, const float* __restrict__ temp,
    __hip_bfloat16* __restrict__ xws)
{
  __shared__ float q_lin[128 * 129];       // [c][129 n-pad] 66 KB
  __shared__ float scratch[2304];          // pstat [2][128][9] -> p32 [8][272]

  int bx = blockIdx.x, t = threadIdx.x;
  int w = t >> 6, l = t & 63;
  int b = bx >> 8, chunk = bx & 255;
  int n0 = chunk * 128;
  int i16 = l & 15, g4 = l >> 4;
  int lj = l & 31, halfw = l >> 5;

  // ---- phase 1: stage 128c x 128n (512 B contiguous per row) + LN partials ----
  const float* gb = outp + (size_t)b * 128 * NN + n0;
  float s4[4] = {0.f, 0.f, 0.f, 0.f}, q24[4] = {0.f, 0.f, 0.f, 0.f};
  int hw = 2 * w + halfw;
#pragma unroll
  for (int p = 0; p < 8; ++p) {
    int c = p * 16 + hw;
    float4 v = *(const float4*)(gb + (size_t)c * NN + lj * 4);
    *(float4*)&q_lin[c * 129 + lj * 4] = v;
    s4[0] += v.x; q24[0] = fmaf(v.x, v.x, q24[0]);
    s4[1] += v.y; q24[1] = fmaf(v.y, v.y, q24[1]);
    s4[2] += v.z; q24[2] = fmaf(v.z, v.z, q24[2]);
    s4[3] += v.w; q24[3] = fmaf(v.w, v.w, q24[3]);
  }
  // combine the wave's two half-waves (same n-quad, different rows)
#pragma unroll
  for (int k2 = 0; k2 < 4; ++k2) {
    s4[k2] += __shfl_xor(s4[k2], 32);
    q24[k2] += __shfl_xor(q24[k2], 32);
  }
  if (halfw == 0) {
#pragma unroll
    for (int k2 = 0; k2 < 4; ++k2) {
      scratch[(4 * lj + k2) * 9 + w] = s4[k2];
      scratch[1152 + (4 * lj + k2) * 9 + w] = q24[k2];
    }
  }

  // ---- per-wave invariants (overlap staging latency) ----
  int h = w & 3, sqb = w >> 2;
  const short* kfb = kfrag + (size_t)((b * 4 + h) * 2048);
  const short* vfb = vfrag + (size_t)((b * 4 + h) * 2048);
  bf16x8 KAh[2], KAl[2], VAh[2], VAl[2];
#pragma unroll
  for (int pt = 0; pt < 2; ++pt) {
    KAh[pt] = *(const bf16x8*)(kfb + pt * 1024 + l * 8);
    KAl[pt] = *(const bf16x8*)(kfb + pt * 1024 + 512 + l * 8);
    VAh[pt] = *(const bf16x8*)(vfb + pt * 1024 + l * 8);
    VAl[pt] = *(const bf16x8*)(vfb + pt * 1024 + 512 + l * 8);
  }
  float w1v[8], b1v[8];
#pragma unroll
  for (int pt = 0; pt < 2; ++pt)
#pragma unroll
    for (int r = 0; r < 4; ++r) {
      int p = g4 * 4 + r + pt * 16;
      w1v[pt * 4 + r] = W1[(b * 4 + h) * 32 + p];
      b1v[pt * 4 + r] = B1[(b * 4 + h) * 32 + p];
    }
  float tm = temp[h];

  __syncthreads();

  // ---- LN finalize: stats for this wave's 4 (unit,nt2) tiles, in regs ----
  float2 mrr[4];
#pragma unroll
  for (int uu = 0; uu < 4; ++uu) {
    int sc2 = sqb + (uu >> 1) * 2;
    int nl = sc2 * 32 + (uu & 1) * 16 + i16;
    float s = 0.f, q2 = 0.f;
#pragma unroll
    for (int j = 0; j < 8; ++j) {
      s  += scratch[nl * 9 + j];
      q2 += scratch[1152 + nl * 9 + j];
    }
    float mu = s * (1.f / 128.f);
    mrr[uu] = make_float2(mu, rsqrtf(q2 * (1.f / 128.f) - mu * mu + LN_EPS));
  }
  __syncthreads();   // all pstat reads done; scratch becomes p32

  unsigned* pwv = (unsigned*)scratch + w * 272;

  // ---- phase 2: two 32-n sub-chunks per wave ----
#pragma unroll
  for (int unit = 0; unit < 2; ++unit) {
    int sc2 = sqb + unit * 2;
    f32x4 Xs[2][2];   // [nt2][kt]
#pragma unroll
    for (int nt2 = 0; nt2 < 2; ++nt2) {
      float2 mr = mrr[unit * 2 + nt2];
      int nloc = sc2 * 32 + nt2 * 16 + i16;

      // B-frag: 8 c-column reads at fixed n (2-way bank aliasing = free)
      float qf[8];
#pragma unroll
      for (int jj = 0; jj < 8; ++jj)
        qf[jj] = q_lin[(h * 32 + g4 * 8 + jj) * 129 + nloc];
      bf16x8 QBh, QBl;
#pragma unroll
      for (int jj = 0; jj < 8; ++jj) {
        short hh, ll; bsplit(qf[jj], hh, ll);
        QBh[jj] = hh; QBl[jj] = ll;
      }

      // QK^T
      f32x4 C[2];
#pragma unroll
      for (int pt = 0; pt < 2; ++pt) {
        C[pt] = (f32x4){0.f, 0.f, 0.f, 0.f};
        C[pt] = __builtin_amdgcn_mfma_f32_16x16x32_bf16(KAh[pt], QBh, C[pt], 0, 0, 0);
        C[pt] = __builtin_amdgcn_mfma_f32_16x16x32_bf16(KAl[pt], QBh, C[pt], 0, 0, 0);
        C[pt] = __builtin_amdgcn_mfma_f32_16x16x32_bf16(KAh[pt], QBl, C[pt], 0, 0, 0);
      }

      // affine finish + temperature; softmax over 32 p
      float lg[8];
#pragma unroll
      for (int pt = 0; pt < 2; ++pt)
#pragma unroll
        for (int r = 0; r < 4; ++r)
          lg[pt * 4 + r] = tm * (mr.y * C[pt][r] - mr.y * mr.x * w1v[pt * 4 + r] + b1v[pt * 4 + r]);
      float mx = lg[0];
#pragma unroll
      for (int i = 1; i < 8; ++i) mx = fmaxf(mx, lg[i]);
      mx = fmaxf(mx, __shfl_xor(mx, 16));
      mx = fmaxf(mx, __shfl_xor(mx, 32));
      float sum = 0.f;
#pragma unroll
      for (int i = 0; i < 8; ++i) { float e = __expf(lg[i] - mx); lg[i] = e; sum += e; }
      sum += __shfl_xor(sum, 16);
      sum += __shfl_xor(sum, 32);
      float inv = 1.f / sum;
#pragma unroll
      for (int i = 0; i < 8; ++i) lg[i] *= inv;

      // P transpose via wave-private LDS, packed bf16x2 words.
#pragma unroll
      for (int pt = 0; pt < 2; ++pt)
#pragma unroll
        for (int pr = 0; pr < 2; ++pr) {
          unsigned wlo = bf16u(lg[pt * 4 + pr * 2]);
          unsigned whi = bf16u(lg[pt * 4 + pr * 2 + 1]);
          pwv[(pt * 8 + g4 * 2 + pr) * 17 + i16] = (whi << 16) | wlo;
        }
      __builtin_amdgcn_wave_barrier();
      bf16x8 PBh;
#pragma unroll
      for (int jw = 0; jw < 4; ++jw) {
        unsigned wv = pwv[(g4 * 4 + jw) * 17 + i16];
        PBh[2 * jw]     = (short)(wv & 0xffffu);
        PBh[2 * jw + 1] = (short)(wv >> 16);
      }
      __builtin_amdgcn_wave_barrier();

      // PV (single-term P; V hi+lo)
#pragma unroll
      for (int kt = 0; kt < 2; ++kt) {
        f32x4 X = (f32x4){0.f, 0.f, 0.f, 0.f};
        X = __builtin_amdgcn_mfma_f32_16x16x32_bf16(VAh[kt], PBh, X, 0, 0, 0);
        X = __builtin_amdgcn_mfma_f32_16x16x32_bf16(VAl[kt], PBh, X, 0, 0, 0);
        Xs[nt2][kt] = X;
      }
    }

    // ---- packed store (round-2 layout): word holds (nt2=0 lo, nt2=1 hi) ----
    short* xwb = (short*)xws + (((size_t)((b * 4 + h) * 32)) << 15)
               + n0 + sc2 * 32 + i16 * 2;
#pragma unroll
    for (int kt = 0; kt < 2; ++kt)
#pragma unroll
      for (int r = 0; r < 4; ++r) {
        int k = kt * 16 + g4 * 4 + r;
        unsigned pkd = ((unsigned)bf16u(Xs[1][kt][r]) << 16) | (unsigned)bf16u(Xs[0][kt][r]);
        *(unsigned*)(xwb + ((size_t)k << 15)) = pkd;
      }
  }
}

// K4: transpose-scatter x_ws -> d_out. grid 2048, block 256.
// Reads the nt2-interleaved xws layout: word at even nhat=2*i2 holds
// n = (2*i2 & ~31) | (i2 & 15)  (lo)  and  n+16  (hi).
__global__ __launch_bounds__(256) void k4_scatter(
    const __hip_bfloat16* __restrict__ xws, float* __restrict__ outd)
{
  __shared__ float tile[64][129];
  int bx = blockIdx.x;
  int tg = bx & 3;
  int k = (bx >> 2) & 31;
  int h = (bx >> 7) & 3;
  int b = bx >> 9;
  int t = threadIdx.x;
  const unsigned* src32 = (const unsigned*)((const short*)xws +
      (((size_t)((b * 4 + h) * 32 + k)) << 15) + tg * 8192);
  for (int i2 = t; i2 < 4096; i2 += 256) {
    unsigned v = src32[i2];
    int loc = ((i2 >> 4) << 5) | (i2 & 15);     // local n (nt2=0 element)
    unsigned lo = v & 0xffffu, hi = v >> 16;
    __hip_bfloat16 blo, bhi;
    __builtin_memcpy(&blo, &lo, 2);
    __builtin_memcpy(&bhi, &hi, 2);
    tile[loc >> 7][loc & 127] = __bfloat162float(blo);
    int loc2 = loc + 16;                        // nt2=1 element (no carry past bit6)
    tile[loc2 >> 7][loc2 & 127] = __bfloat162float(bhi);
  }
  __syncthreads();
  int nh = t & 63, cq = t >> 6;
  size_t obase = (size_t)b * 128 * NN + (size_t)k * 1024 + h * 256 + tg * 64 + nh;
  for (int i = 0; i < 32; ++i) {
    int c0 = i * 4 + cq;
    outd[obase + (size_t)c0 * NN] = tile[nh][c0];
  }
}

extern "C" void kernel_launch(void* const* d_in, const int* in_sizes, int n_in,
                              void* d_out, int out_size, void* d_ws, size_t ws_size,
                              hipStream_t stream) {
  const float* skip = (const float*)d_in[0];
  const float* outp = (const float*)d_in[1];
  const float* gf   = (const float*)d_in[2];
  const float* lnw  = (const float*)d_in[3];
  const float* lnb  = (const float*)d_in[4];
  const float* temp = (const float*)d_in[5];
  const float* EF1  = (const float*)d_in[6];
  const float* EF2  = (const float*)d_in[7];
  float* outd = (float*)d_out;
  char* ws = (char*)d_ws;

  // ws layout (stream-ordered reuse):
  //   [0, 9.44MB)  K1 partials (512 x 4608 f32) - consumed by K2red
  //   [0, 33.5MB)  x_ws bf16 (K3 -> K4), overwrites partials after use
  // d_out doubles as scratch until K4 fully overwrites it (float offsets,
  // verified non-overlapping):
  //   raw   @524288 (16640) -> 540928
  //   W1    @540928 (512)   -> 541440
  //   B1    @541440 (512)   -> 541952
  //   kfrag @541952 (16384 f32 = 32768 shorts) -> 558336
  //   vfrag @558336 (16384) -> 574720  << out_size 16.7M
  __hip_bfloat16* xws = (__hip_bfloat16*)ws;
  float* partials = (float*)ws;
  float* raw   = outd + 524288;
  float* W1    = outd + 540928;
  float* B1    = outd + 541440;
  short* kfrag = (short*)(outd + 541952);
  short* vfrag = (short*)(outd + 558336);

  k1_mfma<<<512, 256, 0, stream>>>(skip, EF2, partials);
  k2_red<<<dim3(130, 4), 256, 0, stream>>>(partials, raw);
  k2_post<<<16, 64, 0, stream>>>(raw, gf, EF1, lnw, lnb, W1, B1, kfrag, vfrag);
  k3_attn<<<1024, 512, 0, stream>>>(outp, kfrag, vfrag, W1, B1, temp, xws);
  k4_scatter<<<2048, 256, 0, stream>>>(xws, outd);
}

// Round 7
// 73.437 us; speedup vs baseline: 1.0407x; 1.0407x over previous
//
#include <hip/hip_runtime.h>
#include <hip/hip_bf16.h>

#define NN 32768
#define LN_EPS 1e-5f

typedef float v4f __attribute__((ext_vector_type(4)));
typedef __attribute__((ext_vector_type(8))) short bf16x8;   // 8 bf16 in 4 VGPRs
typedef __attribute__((ext_vector_type(4))) float f32x4;

// TRUNCATION split: f = hi + lo, bf16 hi = trunc(f), bf16 lo = trunc(f - hi).
__device__ __forceinline__ void bsplit(float f, short &hi, short &lo) {
  unsigned u; __builtin_memcpy(&u, &f, 4);
  unsigned hb = u & 0xffff0000u;
  hi = (short)(u >> 16);
  float hf; __builtin_memcpy(&hf, &hb, 4);
  float lf = f - hf;
  unsigned ul; __builtin_memcpy(&ul, &lf, 4);
  lo = (short)(ul >> 16);
}

// truncation f32 -> bf16 bits.
__device__ __forceinline__ unsigned short bf16u(float f) {
  unsigned u; __builtin_memcpy(&u, &f, 4);
  return (unsigned short)(u >> 16);
}

// K1: kproj partials via MFMA (affine-LN factorization, split-bf16 x3).
// grid 512 (= b(4) x chunk(128) of 256 n), block 256 = 4 waves.
__global__ __launch_bounds__(256) void k1_mfma(
    const float* __restrict__ skip, const float* __restrict__ EF2,
    float* __restrict__ partials)
{
  __shared__ float cred[4752];      // [row<144][33-pad]

  int bx = blockIdx.x, t = threadIdx.x;
  int b = bx >> 7, chunk = bx & 127;
  int w = t >> 6, l = t & 63;
  int i16 = l & 15, kc = (l >> 4) << 3;

  f32x4 acc[9][2];
#pragma unroll
  for (int mt = 0; mt < 9; ++mt)
#pragma unroll
    for (int nt = 0; nt < 2; ++nt)
      acc[mt][nt] = (f32x4){0.f, 0.f, 0.f, 0.f};

#pragma unroll
  for (int it = 0; it < 2; ++it) {
    int n0 = chunk * 256 + w * 64 + it * 32;
    int kt = chunk * 8 + w * 2 + it;

    bf16x8 Bh[2], Bl[2];
    const float* eb = EF2 + (size_t)(kt * 32 + kc) * 32;
#pragma unroll
    for (int nt = 0; nt < 2; ++nt) {
#pragma unroll
      for (int j = 0; j < 8; ++j) {
        float e = eb[(size_t)j * 32 + nt * 16 + i16];
        short hh, ll; bsplit(e, hh, ll);
        Bh[nt][j] = hh; Bl[nt][j] = ll;
      }
    }

    const float* ap = skip + (size_t)(b * 128) * NN + n0 + kc;
    float af[8][8];
#pragma unroll
    for (int mt = 0; mt < 8; ++mt) {
      const float* rp = ap + (size_t)(mt * 16 + i16) * NN;
      float4 a0 = *(const float4*)(rp);
      float4 a1 = *(const float4*)(rp + 4);
      af[mt][0] = a0.x; af[mt][1] = a0.y; af[mt][2] = a0.z; af[mt][3] = a0.w;
      af[mt][4] = a1.x; af[mt][5] = a1.y; af[mt][6] = a1.z; af[mt][7] = a1.w;
    }

    float cs[8], sq[8];
#pragma unroll
    for (int j = 0; j < 8; ++j) {
      float s = 0.f, q = 0.f;
#pragma unroll
      for (int mt = 0; mt < 8; ++mt) { s += af[mt][j]; q = fmaf(af[mt][j], af[mt][j], q); }
      cs[j] = s; sq[j] = q;
    }
#pragma unroll
    for (int m = 1; m <= 8; m <<= 1) {
#pragma unroll
      for (int j = 0; j < 8; ++j) {
        cs[j] += __shfl_xor(cs[j], m);
        sq[j] += __shfl_xor(sq[j], m);
      }
    }
    float rs[8], mr[8];
#pragma unroll
    for (int j = 0; j < 8; ++j) {
      float mu = cs[j] * (1.f / 128.f);
      rs[j] = rsqrtf(sq[j] * (1.f / 128.f) - mu * mu + LN_EPS);
      mr[j] = mu * rs[j];
    }

#pragma unroll
    for (int mt = 0; mt < 8; ++mt) {
      bf16x8 Ah, Al;
#pragma unroll
      for (int j = 0; j < 8; ++j) {
        short h, lo; bsplit(af[mt][j] * rs[j], h, lo);
        Ah[j] = h; Al[j] = lo;
      }
#pragma unroll
      for (int nt = 0; nt < 2; ++nt) {
        acc[mt][nt] = __builtin_amdgcn_mfma_f32_16x16x32_bf16(Ah, Bh[nt], acc[mt][nt], 0, 0, 0);
        acc[mt][nt] = __builtin_amdgcn_mfma_f32_16x16x32_bf16(Al, Bh[nt], acc[mt][nt], 0, 0, 0);
        acc[mt][nt] = __builtin_amdgcn_mfma_f32_16x16x32_bf16(Ah, Bl[nt], acc[mt][nt], 0, 0, 0);
      }
    }
    {
      bf16x8 Ah, Al;
#pragma unroll
      for (int j = 0; j < 8; ++j) {
        float v = (i16 == 0) ? mr[j] : ((i16 == 1) ? 1.f : 0.f);
        short h, lo; bsplit(v, h, lo);
        Ah[j] = h; Al[j] = lo;
      }
#pragma unroll
      for (int nt = 0; nt < 2; ++nt) {
        acc[8][nt] = __builtin_amdgcn_mfma_f32_16x16x32_bf16(Ah, Bh[nt], acc[8][nt], 0, 0, 0);
        acc[8][nt] = __builtin_amdgcn_mfma_f32_16x16x32_bf16(Al, Bh[nt], acc[8][nt], 0, 0, 0);
        acc[8][nt] = __builtin_amdgcn_mfma_f32_16x16x32_bf16(Ah, Bl[nt], acc[8][nt], 0, 0, 0);
      }
    }
  }

  int rbase = (l >> 4) * 4;
  for (int ww = 0; ww < 4; ++ww) {
    __syncthreads();
    if (w == ww) {
#pragma unroll
      for (int mt = 0; mt < 9; ++mt)
#pragma unroll
        for (int nt = 0; nt < 2; ++nt)
#pragma unroll
          for (int r = 0; r < 4; ++r) {
            int addr = (mt * 16 + rbase + r) * 33 + nt * 16 + i16;
            if (ww == 0) cred[addr] = acc[mt][nt][r];
            else         cred[addr] += acc[mt][nt][r];
          }
    }
  }
  __syncthreads();
  float* pw = partials + (size_t)bx * 4608;
#pragma unroll
  for (int i = 0; i < 18; ++i) {
    int idx = t + i * 256;
    pw[idx] = cred[(idx >> 5) * 33 + (idx & 31)];
  }
}

// K2red: reduce 128 chunk-partials per (b,row) for rows 0..129.
// grid dim3(130, 4), block 256.
__global__ __launch_bounds__(256) void k2_red(
    const float* __restrict__ partials, float* __restrict__ raw)
{
  __shared__ float red[8][32];
  int row = blockIdx.x;      // 0..129
  int b   = blockIdx.y;      // 0..3
  int t = threadIdx.x;
  int p = t & 31, grp = t >> 5;
  const float* pp = partials + ((size_t)(b * 128 + grp * 16)) * 4608 + row * 32 + p;
  float s = 0.f;
  for (int i = 0; i < 16; ++i)
    s += pp[(size_t)i * 4608];
  red[grp][p] = s;
  __syncthreads();
  if (t < 32) {
    float tot = 0.f;
#pragma unroll
    for (int g2 = 0; g2 < 8; ++g2) tot += red[g2][t];
    raw[((size_t)b * 130 + row) * 32 + t] = tot;
  }
}

// K2post: per (b,h): affine -> kpw, W1/B1, vproj; pack kfrag/vfrag.
// grid 16, block 64.
__global__ __launch_bounds__(64) void k2_post(
    const float* __restrict__ raw, const float* __restrict__ gf,
    const float* __restrict__ EF1, const float* __restrict__ lnw,
    const float* __restrict__ lnb,
    float* __restrict__ W1, float* __restrict__ B1,
    short* __restrict__ kfrag, short* __restrict__ vfrag)
{
  __shared__ float kpw_s[32][33];   // [d][p]
  __shared__ float vps_s[32][33];   // [p'][k]
  int bh = blockIdx.x, l = threadIdx.x;
  int b = bh >> 2, h = bh & 3;
  int p = l & 31, half = l >> 5;
  const float* rb = raw + (size_t)b * 130 * 32;
  float T = rb[128 * 32 + p];
  float U = rb[129 * 32 + p];
  float w1a = 0.f, b1a = 0.f;
#pragma unroll
  for (int d2 = 0; d2 < 16; ++d2) {
    int d = half * 16 + d2, c = h * 32 + d;
    float tot = rb[c * 32 + p];
    float kp = lnw[c] * (tot - T) + lnb[c] * U;
    float kw = lnw[c] * kp;
    kpw_s[d][p] = kw;
    w1a += kw;
    b1a += lnb[c] * kp;
  }
  w1a += __shfl_xor(w1a, 32);
  b1a += __shfl_xor(b1a, 32);
  if (half == 0) {
    W1[bh * 32 + p] = w1a;
    B1[bh * 32 + p] = b1a;
  }
  {
    float acc[16];
#pragma unroll
    for (int kk = 0; kk < 16; ++kk) acc[kk] = 0.f;
    for (int g = 0; g < 64; ++g) {
      float gv = gf[((size_t)(b * 64 + g)) * 128 + h * 32 + p];
      const float* e1 = EF1 + g * 32 + half * 16;
#pragma unroll
      for (int kk = 0; kk < 16; ++kk) acc[kk] += gv * e1[kk];
    }
#pragma unroll
    for (int kk = 0; kk < 16; ++kk) vps_s[p][half * 16 + kk] = acc[kk];
  }
  __syncthreads();
  int i16 = l & 15, g4 = l >> 4;
#pragma unroll
  for (int pt = 0; pt < 2; ++pt) {
    bf16x8 hi8, lo8;
#pragma unroll
    for (int j = 0; j < 8; ++j) {
      short hh, ll; bsplit(kpw_s[g4 * 8 + j][pt * 16 + i16], hh, ll);
      hi8[j] = hh; lo8[j] = ll;
    }
    *(bf16x8*)(kfrag + (size_t)bh * 2048 + pt * 1024 + l * 8) = hi8;
    *(bf16x8*)(kfrag + (size_t)bh * 2048 + pt * 1024 + 512 + l * 8) = lo8;
  }
#pragma unroll
  for (int kt = 0; kt < 2; ++kt) {
    bf16x8 hi8, lo8;
#pragma unroll
    for (int j = 0; j < 8; ++j) {
      short hh, ll; bsplit(vps_s[g4 * 8 + j][kt * 16 + i16], hh, ll);
      hi8[j] = hh; lo8[j] = ll;
    }
    *(bf16x8*)(vfrag + (size_t)bh * 2048 + kt * 1024 + l * 8) = hi8;
    *(bf16x8*)(vfrag + (size_t)bh * 2048 + kt * 1024 + 512 + l * 8) = lo8;
  }
}

// K3: fused out-LN-stats + attention via MFMA. WAVE = HEAD, 32-n blocks.
// grid 4096 (= b(4) x chunk(1024) of 32 n), block 256 = 4 waves.
// ROUND-7 single change: DE-CLUSTERED chunk->n mapping. Co-resident blocks
// (consecutive bx) get n-windows 1024 n (4 KB) apart via a 5<->5 bit swap,
// so any 32 consecutive blocks span the full 128 KB row -> HBM traffic is
// spread across all channels/DRAM pages instead of concentrating a narrow
// contiguous n-window on a few. Pure bijection: same addresses, same
// numerics, k4 unaffected. Everything else identical to the round-2 kernel.
__global__ __launch_bounds__(256) void k3_attn(
    const float* __restrict__ outp, const short* __restrict__ kfrag,
    const short* __restrict__ vfrag, const float* __restrict__ W1,
    const float* __restrict__ B1, const float* __restrict__ temp,
    __hip_bfloat16* __restrict__ xws)
{
  __shared__ float q_lds[32 * 132];       // [32 n][132 c-pad] 16.9 KB
  __shared__ float2 sst[32];              // {mu, rs} per n
  __shared__ float sstp[4][2][32];        // per-wave LN partials [w][{s,q2}][n]
  __shared__ unsigned p32[4][272];        // [w][wp<16][17-pad] packed P pairs

  int bx = blockIdx.x, t = threadIdx.x;
  int w = t >> 6, l = t & 63;
  int b = bx >> 10;
  int chunkRaw = bx & 1023;
  int chunk = ((chunkRaw & 31) << 5) | (chunkRaw >> 5);   // de-cluster swizzle
  int n0 = chunk * 32;
  int i16 = l & 15, g4 = l >> 4;
  int nq = (t & 7) * 4, cb = t >> 3;

  // ---- stage q slab (128 c x 32 n) + fused LN partial sums ----
  const float* qb = outp + (size_t)b * 128 * NN + n0;
  float s4[4] = {0.f, 0.f, 0.f, 0.f}, q24[4] = {0.f, 0.f, 0.f, 0.f};
#pragma unroll
  for (int pass = 0; pass < 4; ++pass) {
    int c = pass * 32 + cb;
    float4 v = *(const float4*)(qb + (size_t)c * NN + nq);
    q_lds[(nq + 0) * 132 + c] = v.x;
    q_lds[(nq + 1) * 132 + c] = v.y;
    q_lds[(nq + 2) * 132 + c] = v.z;
    q_lds[(nq + 3) * 132 + c] = v.w;
    s4[0] += v.x; q24[0] = fmaf(v.x, v.x, q24[0]);
    s4[1] += v.y; q24[1] = fmaf(v.y, v.y, q24[1]);
    s4[2] += v.z; q24[2] = fmaf(v.z, v.z, q24[2]);
    s4[3] += v.w; q24[3] = fmaf(v.w, v.w, q24[3]);
  }
  // reduce over the 8 lanes of this wave sharing nq (bits 3..5 of t)
#pragma unroll
  for (int m = 8; m <= 32; m <<= 1) {
#pragma unroll
    for (int k = 0; k < 4; ++k) {
      s4[k] += __shfl_xor(s4[k], m);
      q24[k] += __shfl_xor(q24[k], m);
    }
  }
  if ((l & 56) == 0) {   // one writer per (wave, nq)
    *(float4*)&sstp[w][0][nq] = (float4){s4[0], s4[1], s4[2], s4[3]};
    *(float4*)&sstp[w][1][nq] = (float4){q24[0], q24[1], q24[2], q24[3]};
  }
  __syncthreads();
  if (t < 32) {
    float s  = sstp[0][0][t] + sstp[1][0][t] + sstp[2][0][t] + sstp[3][0][t];
    float q2 = sstp[0][1][t] + sstp[1][1][t] + sstp[2][1][t] + sstp[3][1][t];
    float mu = s * (1.f / 128.f);
    float rsv = rsqrtf(q2 * (1.f / 128.f) - mu * mu + LN_EPS);
    sst[t] = make_float2(mu, rsv);
  }
  __syncthreads();

  // ---- wave w = head h, 2 n-tiles ----
  int h = w;
  const short* kfb = kfrag + (size_t)((b * 4 + h) * 2048);
  const short* vfb = vfrag + (size_t)((b * 4 + h) * 2048);
  bf16x8 KAh[2], KAl[2], VAh[2], VAl[2];
#pragma unroll
  for (int pt = 0; pt < 2; ++pt) {
    KAh[pt] = *(const bf16x8*)(kfb + pt * 1024 + l * 8);
    KAl[pt] = *(const bf16x8*)(kfb + pt * 1024 + 512 + l * 8);
    VAh[pt] = *(const bf16x8*)(vfb + pt * 1024 + l * 8);
    VAl[pt] = *(const bf16x8*)(vfb + pt * 1024 + 512 + l * 8);
  }
  float w1v[8], b1v[8];
#pragma unroll
  for (int pt = 0; pt < 2; ++pt)
#pragma unroll
    for (int r = 0; r < 4; ++r) {
      int p = g4 * 4 + r + pt * 16;
      w1v[pt * 4 + r] = W1[(b * 4 + h) * 32 + p];
      b1v[pt * 4 + r] = B1[(b * 4 + h) * 32 + p];
    }
  float tm = temp[h];
  unsigned* pwv = &p32[w][0];
  f32x4 Xs[2][2];   // [nt2][kt] kept for the fused packed store

#pragma unroll
  for (int nt2 = 0; nt2 < 2; ++nt2) {
    int nrow = nt2 * 16 + i16;
    float2 mr = sst[nrow];

    // B-frag: raw q [32d x 16n] from q_lds, 2x b128
    const float* qrow = &q_lds[nrow * 132 + h * 32 + g4 * 8];
    float4 qa = *(const float4*)(qrow);
    float4 qb4 = *(const float4*)(qrow + 4);
    float qf[8] = {qa.x, qa.y, qa.z, qa.w, qb4.x, qb4.y, qb4.z, qb4.w};
    bf16x8 QBh, QBl;
#pragma unroll
    for (int jj = 0; jj < 8; ++jj) {
      short hh, ll; bsplit(qf[jj], hh, ll);
      QBh[jj] = hh; QBl[jj] = ll;
    }

    // QK^T
    f32x4 C[2];
#pragma unroll
    for (int pt = 0; pt < 2; ++pt) {
      C[pt] = (f32x4){0.f, 0.f, 0.f, 0.f};
      C[pt] = __builtin_amdgcn_mfma_f32_16x16x32_bf16(KAh[pt], QBh, C[pt], 0, 0, 0);
      C[pt] = __builtin_amdgcn_mfma_f32_16x16x32_bf16(KAl[pt], QBh, C[pt], 0, 0, 0);
      C[pt] = __builtin_amdgcn_mfma_f32_16x16x32_bf16(KAh[pt], QBl, C[pt], 0, 0, 0);
    }

    // affine finish + temperature; softmax over 32 p
    float lg[8];
#pragma unroll
    for (int pt = 0; pt < 2; ++pt)
#pragma unroll
      for (int r = 0; r < 4; ++r)
        lg[pt * 4 + r] = tm * (mr.y * C[pt][r] - mr.y * mr.x * w1v[pt * 4 + r] + b1v[pt * 4 + r]);
    float mx = lg[0];
#pragma unroll
    for (int i = 1; i < 8; ++i) mx = fmaxf(mx, lg[i]);
    mx = fmaxf(mx, __shfl_xor(mx, 16));
    mx = fmaxf(mx, __shfl_xor(mx, 32));
    float sum = 0.f;
#pragma unroll
    for (int i = 0; i < 8; ++i) { float e = __expf(lg[i] - mx); lg[i] = e; sum += e; }
    sum += __shfl_xor(sum, 16);
    sum += __shfl_xor(sum, 32);
    float inv = 1.f / sum;
#pragma unroll
    for (int i = 0; i < 8; ++i) lg[i] *= inv;

    // P transpose via wave-private LDS, PACKED bf16x2 words.
    // word wp = pt*8 + g4*2 + pr holds p = 2*wp (lo) and 2*wp+1 (hi), col i16.
#pragma unroll
    for (int pt = 0; pt < 2; ++pt)
#pragma unroll
      for (int pr = 0; pr < 2; ++pr) {
        unsigned wlo = bf16u(lg[pt * 4 + pr * 2]);
        unsigned whi = bf16u(lg[pt * 4 + pr * 2 + 1]);
        pwv[(pt * 8 + g4 * 2 + pr) * 17 + i16] = (whi << 16) | wlo;
      }
    __builtin_amdgcn_wave_barrier();
    bf16x8 PBh;
#pragma unroll
    for (int jw = 0; jw < 4; ++jw) {
      unsigned wv = pwv[(g4 * 4 + jw) * 17 + i16];
      PBh[2 * jw]     = (short)(wv & 0xffffu);
      PBh[2 * jw + 1] = (short)(wv >> 16);
    }
    __builtin_amdgcn_wave_barrier();

    // PV (single-term P; V hi+lo)
#pragma unroll
    for (int kt = 0; kt < 2; ++kt) {
      f32x4 X = (f32x4){0.f, 0.f, 0.f, 0.f};
      X = __builtin_amdgcn_mfma_f32_16x16x32_bf16(VAh[kt], PBh, X, 0, 0, 0);
      X = __builtin_amdgcn_mfma_f32_16x16x32_bf16(VAl[kt], PBh, X, 0, 0, 0);
      Xs[nt2][kt] = X;
    }
  }

  // ---- packed store: word at nhat = n0 + i16*2 holds (nt2=0 lo, nt2=1 hi)
  short* xwb = (short*)xws + (((size_t)((b * 4 + h) * 32)) << 15) + n0 + i16 * 2;
#pragma unroll
  for (int kt = 0; kt < 2; ++kt)
#pragma unroll
    for (int r = 0; r < 4; ++r) {
      int k = kt * 16 + g4 * 4 + r;
      unsigned pkd = ((unsigned)bf16u(Xs[1][kt][r]) << 16) | (unsigned)bf16u(Xs[0][kt][r]);
      *(unsigned*)(xwb + ((size_t)k << 15)) = pkd;
    }
}

// K4: transpose-scatter x_ws -> d_out. grid 2048, block 256.
// Reads the nt2-interleaved xws layout: word at even nhat=2*i2 holds
// n = (2*i2 & ~31) | (i2 & 15)  (lo)  and  n+16  (hi).
__global__ __launch_bounds__(256) void k4_scatter(
    const __hip_bfloat16* __restrict__ xws, float* __restrict__ outd)
{
  __shared__ float tile[64][129];
  int bx = blockIdx.x;
  int tg = bx & 3;
  int k = (bx >> 2) & 31;
  int h = (bx >> 7) & 3;
  int b = bx >> 9;
  int t = threadIdx.x;
  const unsigned* src32 = (const unsigned*)((const short*)xws +
      (((size_t)((b * 4 + h) * 32 + k)) << 15) + tg * 8192);
  for (int i2 = t; i2 < 4096; i2 += 256) {
    unsigned v = src32[i2];
    int loc = ((i2 >> 4) << 5) | (i2 & 15);     // local n (nt2=0 element)
    unsigned lo = v & 0xffffu, hi = v >> 16;
    __hip_bfloat16 blo, bhi;
    __builtin_memcpy(&blo, &lo, 2);
    __builtin_memcpy(&bhi, &hi, 2);
    tile[loc >> 7][loc & 127] = __bfloat162float(blo);
    int loc2 = loc + 16;                        // nt2=1 element (no carry past bit6)
    tile[loc2 >> 7][loc2 & 127] = __bfloat162float(bhi);
  }
  __syncthreads();
  int nh = t & 63, cq = t >> 6;
  size_t obase = (size_t)b * 128 * NN + (size_t)k * 1024 + h * 256 + tg * 64 + nh;
  for (int i = 0; i < 32; ++i) {
    int c0 = i * 4 + cq;
    outd[obase + (size_t)c0 * NN] = tile[nh][c0];
  }
}

extern "C" void kernel_launch(void* const* d_in, const int* in_sizes, int n_in,
                              void* d_out, int out_size, void* d_ws, size_t ws_size,
                              hipStream_t stream) {
  const float* skip = (const float*)d_in[0];
  const float* outp = (const float*)d_in[1];
  const float* gf   = (const float*)d_in[2];
  const float* lnw  = (const float*)d_in[3];
  const float* lnb  = (const float*)d_in[4];
  const float* temp = (const float*)d_in[5];
  const float* EF1  = (const float*)d_in[6];
  const float* EF2  = (const float*)d_in[7];
  float* outd = (float*)d_out;
  char* ws = (char*)d_ws;

  // ws layout (stream-ordered reuse):
  //   [0, 9.44MB)  K1 partials (512 x 4608 f32) - consumed by K2red
  //   [0, 33.5MB)  x_ws bf16 (K3 -> K4), overwrites partials after use
  // d_out doubles as scratch until K4 fully overwrites it (float offsets,
  // verified non-overlapping):
  //   raw   @524288 (16640) -> 540928
  //   W1    @540928 (512)   -> 541440
  //   B1    @541440 (512)   -> 541952
  //   kfrag @541952 (16384 f32 = 32768 shorts) -> 558336
  //   vfrag @558336 (16384) -> 574720  << out_size 16.7M
  __hip_bfloat16* xws = (__hip_bfloat16*)ws;
  float* partials = (float*)ws;
  float* raw   = outd + 524288;
  float* W1    = outd + 540928;
  float* B1    = outd + 541440;
  short* kfrag = (short*)(outd + 541952);
  short* vfrag = (short*)(outd + 558336);

  k1_mfma<<<512, 256, 0, stream>>>(skip, EF2, partials);
  k2_red<<<dim3(130, 4), 256, 0, stream>>>(partials, raw);
  k2_post<<<16, 64, 0, stream>>>(raw, gf, EF1, lnw, lnb, W1, B1, kfrag, vfrag);
  k3_attn<<<4096, 256, 0, stream>>>(outp, kfrag, vfrag, W1, B1, temp, xws);
  k4_scatter<<<2048, 256, 0, stream>>>(xws, outd);
}